// Round 13
// baseline (272.983 us; speedup 1.0000x reference)
//
#include <hip/hip_runtime.h>
#include <hip/hip_bf16.h>

// ---------------- problem constants ----------------
#define B_N 2
#define L_N 8192
#define ROWS 16384                // B_N * L_N
#define CHUNK 32
#define NCHUNK 256                // L_N / CHUNK
#define NPAD 1152                 // input-proj N padded: 2 x 544 + pad to 9*128

typedef __bf16 bf16x8 __attribute__((ext_vector_type(8)));
typedef float f32x4 __attribute__((ext_vector_type(4)));

// fast silu: 1-ulp rcp instead of IEEE divide
__device__ __forceinline__ float siluf(float v) {
  return v * __builtin_amdgcn_rcpf(1.f + __expf(-v));
}
__device__ __forceinline__ float softplusf_(float v) {
  return fmaxf(v, 0.f) + log1pf(__expf(-fabsf(v)));
}
// native bf16 convert (gfx950 HW cvt, RNE)
__device__ __forceinline__ unsigned short f2bf(float v) {
  union { __bf16 b; unsigned short u; } x;
  x.b = (__bf16)v;
  return x.u;
}
__device__ __forceinline__ float bf2f(unsigned short u) {
  union { unsigned u; float f; } x; x.u = ((unsigned)u) << 16;
  return x.f;
}

// async global->LDS, 16B per lane, LDS dest = wave-uniform base + lane*16
__device__ __forceinline__ void gload_lds16(const unsigned short* g, unsigned short* l) {
  __builtin_amdgcn_global_load_lds(
      (const __attribute__((address_space(1))) unsigned int*)g,
      (__attribute__((address_space(3))) unsigned int*)l, 16, 0, 0);
}

struct P4 { const float* p[4]; };

// ---------------- prep (weights + inv only; x handled by k_dtfix) ----------------
// blocks [0,2304): Wt_in; [2304,3328): Wt_dirs; [3328,4352): Wt_fin; [4352,4416): inv
__global__ void k_prep_all(const float* __restrict__ WH, const float* __restrict__ WV,
                           P4 ws, const float* __restrict__ W_out, const int* __restrict__ v2h,
                           unsigned short* __restrict__ Wt_in,
                           unsigned short* __restrict__ Wt_dirs, unsigned short* __restrict__ Wt_fin,
                           int* __restrict__ inv) {
  int bid = blockIdx.x;
  int tid = threadIdx.x;
  if (bid < 2304) {
    int i = bid * 256 + tid;                  // 2*1152*256
    int z = i / (NPAD * 256);
    int rem = i - z * (NPAD * 256);
    int n = rem >> 8, k = rem & 255;
    const float* W = z ? WV : WH;
    int sl = n >= 544;
    int cc = n - (sl ? 544 : 0);
    float v = (cc < 532) ? W[(long)k * 1064 + sl * 532 + cc] : 0.f;
    Wt_in[i] = f2bf(v);
  } else if (bid < 3328) {
    int i = (bid - 2304) * 256 + tid;         // 4*65536
    int d = i >> 16;
    int rem = i & 65535;
    int n = rem >> 8, k = rem & 255;
    Wt_dirs[i] = f2bf(ws.p[d][(long)k * 256 + n]);
  } else if (bid < 4352) {
    int i = (bid - 3328) * 256 + tid;         // 256*1024, i = n*1024+k
    int n = i >> 10, k = i & 1023;
    Wt_fin[i] = f2bf(W_out[(long)k * 256 + n]);
  } else {
    int m = (bid - 4352) * 256 + tid;
    if (m < ROWS) {
      int b = m >> 13;
      inv[b * L_N + v2h[m]] = m;              // inverse of the v->h scatter
    }
  }
}

struct ScanConsts {
  const float* dt_bias[4];
  const float* A_log[4];
  const float* D[4];
};

// exact fp32 dt dot with LDS staging; precompute dtv/dA; ALSO writes xbf (bf16 cvt of x)
__global__ __launch_bounds__(256) void k_dtfix(
    const float* __restrict__ xH, const float* __restrict__ xV,
    const float* __restrict__ WH, const float* __restrict__ WV,
    ScanConsts sc, float* __restrict__ dtv_arr, float* __restrict__ dA_arr,
    unsigned short* __restrict__ xbf) {
  __shared__ float xs[32][257];
  __shared__ float Wsm[8][260];
  const int mat = blockIdx.y;
  const float* x = mat ? xV : xH;
  const float* W = mat ? WV : WH;
  const int r0 = blockIdx.x * 32;
  for (int i = threadIdx.x; i < 2048; i += 256) {
    int c = i >> 8, k = i & 255;              // c = sl*4+h
    int sl = c >> 2, h = c & 3;
    Wsm[c][k] = W[(long)k * 1064 + sl * 532 + 528 + h];
  }
  for (int i = threadIdx.x; i < 32 * 64; i += 256) {
    int rl = i >> 6, kq = (i & 63) * 4;
    float4 v = *(const float4*)(x + (long)(r0 + rl) * 256 + kq);
    xs[rl][kq + 0] = v.x; xs[rl][kq + 1] = v.y; xs[rl][kq + 2] = v.z; xs[rl][kq + 3] = v.w;
  }
  __syncthreads();
  // bf16 conversion of the staged x tile -> xbf
  for (int i = threadIdx.x; i < 32 * 64; i += 256) {
    int rl = i >> 6, kq = (i & 63) * 4;
    ushort4 o;
    o.x = f2bf(xs[rl][kq + 0]);
    o.y = f2bf(xs[rl][kq + 1]);
    o.z = f2bf(xs[rl][kq + 2]);
    o.w = f2bf(xs[rl][kq + 3]);
    *(ushort4*)(xbf + (size_t)mat * ROWS * 256 + (long)(r0 + rl) * 256 + kq) = o;
  }
  const int rl = threadIdx.x >> 3, c = threadIdx.x & 7;
  float s = 0.f;
  #pragma unroll 8
  for (int k = 0; k < 256; ++k) s = fmaf(xs[rl][k], Wsm[c][k], s);
  const int sl = c >> 2, h = c & 3;
  const int dir = mat * 2 + sl;
  float dtv = softplusf_(s + sc.dt_bias[dir][h]);
  float dAv = __expf(dtv * (-__expf(sc.A_log[dir][h])));
  long o = ((long)dir * 4 + h) * ROWS + (r0 + rl);
  dtv_arr[o] = dtv;
  dA_arr[o] = dAv;
}

// ---------------- bf16 MFMA GEMM (128x128 tile, BK=32, async LDS staging) ----------------
struct EpiIn {
  unsigned short* zraw;   // [4][ROWS*256] raw z (silu applied in scans)
  unsigned short* xraw;   // [4][ROWS*256] raw x
  unsigned short* bc;     // [4][ROWS*16]  raw B|C
};

// input-proj GEMM: A row-major bf16 (lda=K=256), Bt [n][k]. Routing epilogue via
// per-wave 16-row LDS transpose; NO silu (moved to scans). Grid: x=rows, y=cols, z=mat.
__global__ __launch_bounds__(256) void k_gemm_in(
    const unsigned short* __restrict__ Abase, const unsigned short* __restrict__ Btbase,
    EpiIn ep) {
  __shared__ unsigned short As[128 * 32];
  __shared__ unsigned short Bs[128 * 32];
  __shared__ unsigned short trs[4][16 * 72];
  const int tid = threadIdx.x;
  const int lane = tid & 63;
  const int wid = tid >> 6;
  const int wm = wid & 1, wn = wid >> 1;
  const int q = lane >> 4, r = lane & 15;
  const int m0 = blockIdx.x * 128;
  const int n0 = blockIdx.y * 128;
  const int z = blockIdx.z;
  const unsigned short* A = Abase + (long)z * ROWS * 256;
  const unsigned short* Bt = Btbase + (long)z * NPAD * 256;

  f32x4 acc[4][4] = {};
  const int swr = (r >> 1) & 3;               // read-side swizzle

  for (int kt = 0; kt < 256; kt += 32) {
    #pragma unroll
    for (int i = 0; i < 2; ++i) {
      int idx = i * 256 + tid;
      int row = idx >> 2;
      int ch = (idx & 3) ^ ((row >> 1) & 3);
      gload_lds16(A + (long)(m0 + row) * 256 + kt + ch * 8,
                  &As[(size_t)(i * 256 + wid * 64) * 8]);
    }
    #pragma unroll
    for (int i = 0; i < 2; ++i) {
      int idx = i * 256 + tid;
      int row = idx >> 2;
      int ch = (idx & 3) ^ ((row >> 1) & 3);
      gload_lds16(Bt + (long)(n0 + row) * 256 + kt + ch * 8,
                  &Bs[(size_t)(i * 256 + wid * 64) * 8]);
    }
    __syncthreads();
    bf16x8 af[4], bfr[4];
    #pragma unroll
    for (int mi = 0; mi < 4; ++mi)
      af[mi] = *(const bf16x8*)&As[((wm * 64 + mi * 16 + r) * 4 + (q ^ swr)) * 8];
    #pragma unroll
    for (int ni = 0; ni < 4; ++ni)
      bfr[ni] = *(const bf16x8*)&Bs[((wn * 64 + ni * 16 + r) * 4 + (q ^ swr)) * 8];
    #pragma unroll
    for (int mi = 0; mi < 4; ++mi)
      #pragma unroll
      for (int ni = 0; ni < 4; ++ni)
        acc[mi][ni] = __builtin_amdgcn_mfma_f32_16x16x32_bf16(af[mi], bfr[ni], acc[mi][ni], 0, 0, 0);
    __syncthreads();
  }

  // per-wave dedicated transpose region: 16 rows x 72 cols (raw bf16, no silu)
  unsigned short* tr = trs[wid];
  #pragma unroll
  for (int mi = 0; mi < 4; ++mi) {
    #pragma unroll
    for (int ni = 0; ni < 4; ++ni)
      #pragma unroll
      for (int j = 0; j < 4; ++j)
        tr[(q * 4 + j) * 72 + ni * 16 + r] = f2bf(acc[mi][ni][j]);
    asm volatile("s_waitcnt lgkmcnt(0)" ::: "memory");
    #pragma unroll
    for (int pass = 0; pass < 2; ++pass) {
      int rl = pass * 8 + (lane >> 3);
      int c8 = (lane & 7) * 8;
      bf16x8 v = *(const bf16x8*)&tr[rl * 72 + c8];
      int row = m0 + wm * 64 + mi * 16 + rl;
      int col = n0 + wn * 64 + c8;
      int sl = col >= 544;
      int cc = col - (sl ? 544 : 0);
      if (cc < 528) {
        int dir = z * 2 + sl;
        if (cc < 256)
          *(bf16x8*)(ep.zraw + ((long)dir * ROWS + row) * 256 + cc) = v;
        else if (cc < 512)
          *(bf16x8*)(ep.xraw + ((long)dir * ROWS + row) * 256 + cc - 256) = v;
        else
          *(bf16x8*)(ep.bc + ((long)dir * ROWS + row) * 16 + cc - 512) = v;
      }
    }
    asm volatile("s_waitcnt lgkmcnt(0)" ::: "memory");
  }
}

// ---------------- fused out-proj + final GEMM, split by dir pair ----------------
__global__ __launch_bounds__(256) void k_fuse(
    const unsigned short* __restrict__ ybf,      // [4][ROWS][256]
    const unsigned short* __restrict__ Wt_dirs,  // [4][256 n][256 k]
    const unsigned short* __restrict__ Wt_fin,   // [256 c][1024 k] (k = d*256+kk)
    const int* __restrict__ inv,
    unsigned short* __restrict__ pbuf) {         // [2][ROWS*256] bf16
  __shared__ unsigned short Tl[64][264];         // silu'd T, row-major, pad 264
  __shared__ unsigned short As1[64 * 32];        // y-tile staging
  __shared__ unsigned short Bs1[256 * 32];       // weight staging (both gemms)
  __shared__ int arow[64];
  const int tid = threadIdx.x;
  const int lane = tid & 63;
  const int wid = tid >> 6;
  const int q = lane >> 4, r = lane & 15;
  const int r0 = blockIdx.x * 64;
  const int pair = blockIdx.y;
  const int swr = (r >> 1) & 3;

  if (tid < 64) arow[tid] = pair ? inv[r0 + tid] : (r0 + tid);
  __syncthreads();

  f32x4 acc_o[4][4] = {};

  #pragma unroll
  for (int dd = 0; dd < 2; ++dd) {
    const int d = pair * 2 + dd;
    const unsigned short* yd = ybf + (long)d * ROWS * 256;
    const unsigned short* Wd = Wt_dirs + (long)d * 65536;

    f32x4 acc_t[4][4] = {};
    // ---- first GEMM: T = y_d[rows,:] @ Wd  (K=256) ----
    for (int kt = 0; kt < 256; kt += 32) {
      {
        int row = tid >> 2;
        int ch = (tid & 3) ^ ((row >> 1) & 3);
        gload_lds16(yd + (long)arow[row] * 256 + kt + ch * 8, &As1[(size_t)(wid * 64) * 8]);
      }
      #pragma unroll
      for (int i = 0; i < 4; ++i) {
        int idx = i * 256 + tid;
        int row = idx >> 2;
        int ch = (idx & 3) ^ ((row >> 1) & 3);
        gload_lds16(Wd + (long)row * 256 + kt + ch * 8,
                    &Bs1[(size_t)(i * 256 + wid * 64) * 8]);
      }
      __syncthreads();
      bf16x8 af[4], bfr[4];
      #pragma unroll
      for (int mi = 0; mi < 4; ++mi)
        af[mi] = *(const bf16x8*)&As1[((mi * 16 + r) * 4 + (q ^ swr)) * 8];
      #pragma unroll
      for (int ni = 0; ni < 4; ++ni)
        bfr[ni] = *(const bf16x8*)&Bs1[((wid * 64 + ni * 16 + r) * 4 + (q ^ swr)) * 8];
      #pragma unroll
      for (int mi = 0; mi < 4; ++mi)
        #pragma unroll
        for (int ni = 0; ni < 4; ++ni)
          acc_t[mi][ni] = __builtin_amdgcn_mfma_f32_16x16x32_bf16(af[mi], bfr[ni], acc_t[mi][ni], 0, 0, 0);
      __syncthreads();
    }
    // ---- write silu(T) to LDS (row-major) ----
    #pragma unroll
    for (int mi = 0; mi < 4; ++mi)
      #pragma unroll
      for (int ni = 0; ni < 4; ++ni)
        #pragma unroll
        for (int j = 0; j < 4; ++j)
          Tl[mi * 16 + q * 4 + j][wid * 64 + ni * 16 + r] = f2bf(siluf(acc_t[mi][ni][j]));
    __syncthreads();
    // ---- second GEMM: acc_o += T @ Wout[d*256+kk][c], A from Tl ----
    for (int kt = 0; kt < 256; kt += 32) {
      #pragma unroll
      for (int i = 0; i < 4; ++i) {
        int idx = i * 256 + tid;
        int row = idx >> 2;                    // out col c
        int ch = (idx & 3) ^ ((row >> 1) & 3);
        gload_lds16(Wt_fin + (long)row * 1024 + d * 256 + kt + ch * 8,
                    &Bs1[(size_t)(i * 256 + wid * 64) * 8]);
      }
      __syncthreads();
      bf16x8 af[4], bfr[4];
      #pragma unroll
      for (int mi = 0; mi < 4; ++mi)
        af[mi] = *(const bf16x8*)&Tl[mi * 16 + r][kt + q * 8];
      #pragma unroll
      for (int ni = 0; ni < 4; ++ni)
        bfr[ni] = *(const bf16x8*)&Bs1[((wid * 64 + ni * 16 + r) * 4 + (q ^ swr)) * 8];
      #pragma unroll
      for (int mi = 0; mi < 4; ++mi)
        #pragma unroll
        for (int ni = 0; ni < 4; ++ni)
          acc_o[mi][ni] = __builtin_amdgcn_mfma_f32_16x16x32_bf16(af[mi], bfr[ni], acc_o[mi][ni], 0, 0, 0);
      __syncthreads();
    }
  }

  // ---- output: bf16 partial via Tl transpose (wave-internal band), 16B/lane stores ----
  #pragma unroll
  for (int mi = 0; mi < 4; ++mi)
    #pragma unroll
    for (int ni = 0; ni < 4; ++ni)
      #pragma unroll
      for (int j = 0; j < 4; ++j)
        Tl[mi * 16 + q * 4 + j][wid * 64 + ni * 16 + r] = f2bf(acc_o[mi][ni][j]);
  asm volatile("s_waitcnt lgkmcnt(0)" ::: "memory");
  unsigned short* pout = pbuf + (long)pair * ROWS * 256;
  #pragma unroll
  for (int pass = 0; pass < 8; ++pass) {
    int rl = pass * 8 + (lane >> 3);
    int c8 = (lane & 7) * 8;
    bf16x8 v = *(const bf16x8*)&Tl[rl][wid * 64 + c8];
    *(bf16x8*)(pout + (long)(r0 + rl) * 256 + wid * 64 + c8) = v;
  }
}

// sum the two bf16 pair partials into fp32 d_out
__global__ void k_red(const unsigned short* __restrict__ pbuf, float* __restrict__ out) {
  int i = blockIdx.x * 256 + threadIdx.x;     // 8-elem group index, ROWS*256/8 total
  uint4 a = ((const uint4*)pbuf)[i];
  uint4 b = ((const uint4*)(pbuf + (size_t)ROWS * 256))[i];
  const unsigned short* au = (const unsigned short*)&a;
  const unsigned short* bu = (const unsigned short*)&b;
  float rr[8];
  #pragma unroll
  for (int j = 0; j < 8; ++j) rr[j] = bf2f(au[j]) + bf2f(bu[j]);
  ((float4*)out)[i * 2] = *(float4*)&rr[0];
  ((float4*)out)[i * 2 + 1] = *(float4*)&rr[4];
}

// ---------------- scan kernels ----------------
struct ScanP {
  const unsigned short* xraw;  // [4][ROWS*256] raw (silu applied here)
  const unsigned short* zraw;
  const unsigned short* bc;    // [4][ROWS*16] raw
  const float* dtv;            // [16][ROWS]  (dir*4+h)
  const float* dA;
  const float* D[4];
};

// phase 1: per-chunk (32 steps) local scan from zero; write end-state S and cum-dA P
__global__ __launch_bounds__(64) void k_scan1(ScanP sp, float* __restrict__ S,
                                              float* __restrict__ P) {
  __shared__ __align__(16) float Bst[CHUNK][8];
  __shared__ float dAs[CHUNK];
  const int p = threadIdx.x;
  const int c = blockIdx.x;
  const int bh = blockIdx.y;
  const int d = blockIdx.z;
  const int b = bh >> 2, h = bh & 3;
  const int rev = d & 1;
  const int t0 = c * CHUNK;
  if (p < CHUNK) {
    const int t = t0 + p;
    const int l = rev ? (L_N - 1 - t) : t;
    const int row = (b << 13) + l;
    uint4 bv = *(const uint4*)(sp.bc + ((long)d * ROWS + row) * 16);
    const unsigned short* bu = (const unsigned short*)&bv;
    float dtvv = sp.dtv[((long)d * 4 + h) * ROWS + row];
    dAs[p] = sp.dA[((long)d * 4 + h) * ROWS + row];
    #pragma unroll
    for (int n = 0; n < 8; ++n) Bst[p][n] = siluf(bf2f(bu[n])) * dtvv;
  }
  __syncthreads();

  float st[8] = {0, 0, 0, 0, 0, 0, 0, 0};
  float cumdA = 1.f;
  const int l0 = rev ? (L_N - 1 - t0) : t0;
  const unsigned short* xp = sp.xraw + ((long)d * ROWS + (b << 13) + l0) * 256 + h * 64 + p;
  const long stp = rev ? -256L : 256L;

  // double-buffered 8-step load groups
  unsigned short xa[8], xb[8];
  #pragma unroll
  for (int j = 0; j < 8; ++j) xa[j] = xp[(long)j * stp];
  #pragma unroll
  for (int g = 0; g < 4; ++g) {
    if (g < 3) {
      #pragma unroll
      for (int j = 0; j < 8; ++j) xb[j] = xp[(long)((g + 1) * 8 + j) * stp];
    }
    #pragma unroll
    for (int j = 0; j < 8; ++j) {
      int s = g * 8 + j;
      float x = siluf(bf2f(xa[j]));
      float dA = dAs[s];
      f32x4 B0 = *(const f32x4*)&Bst[s][0];
      f32x4 B1 = *(const f32x4*)&Bst[s][4];
      cumdA *= dA;
      st[0] = fmaf(dA, st[0], x * B0[0]);
      st[1] = fmaf(dA, st[1], x * B0[1]);
      st[2] = fmaf(dA, st[2], x * B0[2]);
      st[3] = fmaf(dA, st[3], x * B0[3]);
      st[4] = fmaf(dA, st[4], x * B1[0]);
      st[5] = fmaf(dA, st[5], x * B1[1]);
      st[6] = fmaf(dA, st[6], x * B1[2]);
      st[7] = fmaf(dA, st[7], x * B1[3]);
    }
    #pragma unroll
    for (int j = 0; j < 8; ++j) xa[j] = xb[j];
  }
  float* Sp = S + ((((long)d * NCHUNK + c) * 8 + bh) * 64 + p) * 8;
  #pragma unroll
  for (int n = 0; n < 8; ++n) Sp[n] = st[n];
  if (p == 0) P[((long)d * NCHUNK + c) * 8 + bh] = cumdA;
}

// phase 2: sequential chunk-level combine -> carry-in per chunk (P preloaded to LDS)
__global__ __launch_bounds__(512) void k_scan2(const float* __restrict__ S,
                                               const float* __restrict__ P,
                                               float* __restrict__ carry) {
  __shared__ float Pl[NCHUNK];
  const int tid = threadIdx.x;
  const int dbh = blockIdx.x;
  const int d = dbh >> 3, bh = dbh & 7;
  if (tid < NCHUNK) Pl[tid] = P[((long)d * NCHUNK + tid) * 8 + bh];
  __syncthreads();
  float cy = 0.f;
  carry[(((long)d * NCHUNK + 0) * 8 + bh) * 512 + tid] = 0.f;
  #pragma unroll 8
  for (int c = 1; c < NCHUNK; ++c) {
    const float Sv = S[(((long)d * NCHUNK + (c - 1)) * 8 + bh) * 512 + tid];
    cy = fmaf(Pl[c - 1], cy, Sv);
    carry[(((long)d * NCHUNK + c) * 8 + bh) * 512 + tid] = cy;
  }
}

// phase 3: re-scan with carry-in, produce gated y in bf16
__global__ __launch_bounds__(64) void k_scan3(ScanP sp, const float* __restrict__ carry,
                                              unsigned short* __restrict__ ybf) {
  __shared__ __align__(16) float Bst[CHUNK][8];
  __shared__ __align__(16) float Cst[CHUNK][8];
  __shared__ float dAs[CHUNK];
  const int p = threadIdx.x;
  const int c = blockIdx.x;
  const int bh = blockIdx.y;
  const int d = blockIdx.z;
  const int b = bh >> 2, h = bh & 3;
  const int rev = d & 1;
  const float Dv = sp.D[d][h];
  const int t0 = c * CHUNK;
  if (p < CHUNK) {
    const int t = t0 + p;
    const int l = rev ? (L_N - 1 - t) : t;
    const int row = (b << 13) + l;
    const unsigned short* bp = sp.bc + ((long)d * ROWS + row) * 16;
    uint4 bv = *(const uint4*)bp;
    uint4 cv = *(const uint4*)(bp + 8);
    const unsigned short* bu = (const unsigned short*)&bv;
    const unsigned short* cu = (const unsigned short*)&cv;
    float dtvv = sp.dtv[((long)d * 4 + h) * ROWS + row];
    dAs[p] = sp.dA[((long)d * 4 + h) * ROWS + row];
    #pragma unroll
    for (int n = 0; n < 8; ++n) Bst[p][n] = siluf(bf2f(bu[n])) * dtvv;
    #pragma unroll
    for (int n = 0; n < 8; ++n) Cst[p][n] = siluf(bf2f(cu[n]));
  }
  __syncthreads();

  float st[8];
  {
    const float* cp = carry + ((((long)d * NCHUNK + c) * 8 + bh) * 64 + p) * 8;
    #pragma unroll
    for (int n = 0; n < 8; ++n) st[n] = cp[n];
  }

  const int l0 = rev ? (L_N - 1 - t0) : t0;
  const long base = (long)(b << 13) + l0;
  const unsigned short* xp = sp.xraw + ((long)d * ROWS + base) * 256 + h * 64 + p;
  const unsigned short* zp = sp.zraw + ((long)d * ROWS + base) * 256 + h * 64 + p;
  unsigned short* yp = ybf + ((long)d * ROWS + base) * 256 + h * 64 + p;
  const long stp = rev ? -256L : 256L;

  // double-buffered 8-step load groups (x and z)
  unsigned short xa[8], xb[8], za[8], zb[8];
  #pragma unroll
  for (int j = 0; j < 8; ++j) { xa[j] = xp[(long)j * stp]; za[j] = zp[(long)j * stp]; }
  #pragma unroll
  for (int g = 0; g < 4; ++g) {
    if (g < 3) {
      #pragma unroll
      for (int j = 0; j < 8; ++j) {
        xb[j] = xp[(long)((g + 1) * 8 + j) * stp];
        zb[j] = zp[(long)((g + 1) * 8 + j) * stp];
      }
    }
    #pragma unroll
    for (int j = 0; j < 8; ++j) {
      int s = g * 8 + j;
      float x = siluf(bf2f(xa[j]));
      float zv = siluf(bf2f(za[j]));
      float dA = dAs[s];
      f32x4 B0 = *(const f32x4*)&Bst[s][0];
      f32x4 B1 = *(const f32x4*)&Bst[s][4];
      f32x4 C0 = *(const f32x4*)&Cst[s][0];
      f32x4 C1 = *(const f32x4*)&Cst[s][4];
      st[0] = fmaf(dA, st[0], x * B0[0]);
      st[1] = fmaf(dA, st[1], x * B0[1]);
      st[2] = fmaf(dA, st[2], x * B0[2]);
      st[3] = fmaf(dA, st[3], x * B0[3]);
      st[4] = fmaf(dA, st[4], x * B1[0]);
      st[5] = fmaf(dA, st[5], x * B1[1]);
      st[6] = fmaf(dA, st[6], x * B1[2]);
      st[7] = fmaf(dA, st[7], x * B1[3]);
      float y01 = fmaf(st[1], C0[1], st[0] * C0[0]);
      float y23 = fmaf(st[3], C0[3], st[2] * C0[2]);
      float y45 = fmaf(st[5], C1[1], st[4] * C1[0]);
      float y67 = fmaf(st[7], C1[3], st[6] * C1[2]);
      float y = (y01 + y23) + (y45 + y67);
      y = fmaf(Dv, x, y) * zv;
      yp[(long)s * stp] = f2bf(y);
    }
    #pragma unroll
    for (int j = 0; j < 8; ++j) { xa[j] = xb[j]; za[j] = zb[j]; }
  }
}

// ---------------- launch ----------------
extern "C" void kernel_launch(void* const* d_in, const int* in_sizes, int n_in,
                              void* d_out, int out_size, void* d_ws, size_t ws_size,
                              hipStream_t stream) {
  const float* x_H = (const float*)d_in[0];
  const float* x_V = (const float*)d_in[1];
  const float* W_in_H = (const float*)d_in[2];
  const float* W_in_V = (const float*)d_in[3];
  const float* W_out_HF = (const float*)d_in[4];
  const float* W_out_HB = (const float*)d_in[5];
  const float* W_out_VF = (const float*)d_in[6];
  const float* W_out_VB = (const float*)d_in[7];
  const float* W_out = (const float*)d_in[8];
  const float* dt_bias_HF = (const float*)d_in[9];
  const float* A_log_HF = (const float*)d_in[10];
  const float* D_HF = (const float*)d_in[11];
  const float* dt_bias_HB = (const float*)d_in[12];
  const float* A_log_HB = (const float*)d_in[13];
  const float* D_HB = (const float*)d_in[14];
  const float* dt_bias_VF = (const float*)d_in[15];
  const float* A_log_VF = (const float*)d_in[16];
  const float* D_VF = (const float*)d_in[17];
  const float* dt_bias_VB = (const float*)d_in[18];
  const float* A_log_VB = (const float*)d_in[19];
  const float* D_VB = (const float*)d_in[20];
  const int* v2h = (const int*)d_in[21];

  char* ws = (char*)d_ws;
  size_t off = 0;
  auto alloc = [&](size_t bytes) {
    void* pp = ws + off;
    off = (off + bytes + 255) & ~(size_t)255;
    return pp;
  };
  unsigned short* xbf = (unsigned short*)alloc((size_t)2 * ROWS * 256 * 2);      // [2 mats]
  unsigned short* Wt_in = (unsigned short*)alloc((size_t)2 * NPAD * 256 * 2);    // [2 mats]
  unsigned short* Wt_dirs = (unsigned short*)alloc((size_t)4 * 65536 * 2);
  unsigned short* Wt_fin = (unsigned short*)alloc((size_t)256 * 1024 * 2);
  unsigned short* zraw = (unsigned short*)alloc((size_t)4 * ROWS * 256 * 2);
  unsigned short* xraw = (unsigned short*)alloc((size_t)4 * ROWS * 256 * 2);
  unsigned short* bc = (unsigned short*)alloc((size_t)4 * ROWS * 16 * 2);
  float* dtv_arr = (float*)alloc((size_t)16 * ROWS * 4);
  float* dA_arr = (float*)alloc((size_t)16 * ROWS * 4);
  unsigned short* ybf = (unsigned short*)alloc((size_t)4 * ROWS * 256 * 2);
  float* S = (float*)alloc((size_t)4 * NCHUNK * 8 * 512 * 4);
  float* P = (float*)alloc((size_t)4 * NCHUNK * 8 * 4);
  float* carry = (float*)alloc((size_t)4 * NCHUNK * 8 * 512 * 4);
  int* inv = (int*)alloc((size_t)ROWS * 4);
  unsigned short* pbuf = (unsigned short*)alloc((size_t)2 * ROWS * 256 * 2);

  ScanConsts sc;
  sc.dt_bias[0] = dt_bias_HF; sc.dt_bias[1] = dt_bias_HB;
  sc.dt_bias[2] = dt_bias_VF; sc.dt_bias[3] = dt_bias_VB;
  sc.A_log[0] = A_log_HF; sc.A_log[1] = A_log_HB;
  sc.A_log[2] = A_log_VF; sc.A_log[3] = A_log_VB;
  sc.D[0] = D_HF; sc.D[1] = D_HB; sc.D[2] = D_VF; sc.D[3] = D_VB;

  P4 wdirs;  // cat order: dir0 HF->W_out_HB, dir1 HB->W_out_HF, dir2 VF->W_out_VB, dir3 VB->W_out_VF
  wdirs.p[0] = W_out_HB; wdirs.p[1] = W_out_HF; wdirs.p[2] = W_out_VB; wdirs.p[3] = W_out_VF;
  // weights + inv prep (x conversion moved into k_dtfix)
  k_prep_all<<<4416, 256, 0, stream>>>(W_in_H, W_in_V, wdirs, W_out, v2h,
                                       Wt_in, Wt_dirs, Wt_fin, inv);
  // exact fp32 dt -> dtv, dA; also converts x -> xbf
  k_dtfix<<<dim3(ROWS / 32, 2), 256, 0, stream>>>(x_H, x_V, W_in_H, W_in_V, sc,
                                                  dtv_arr, dA_arr, xbf);

  EpiIn ep; ep.zraw = zraw; ep.xraw = xraw; ep.bc = bc;

  // input GEMMs (batched over 2 mats), routing epilogue -> raw bf16 z/x/bc
  k_gemm_in<<<dim3(ROWS / 128, NPAD / 128, 2), 256, 0, stream>>>(xbf, Wt_in, ep);

  ScanP sp;
  sp.xraw = xraw; sp.zraw = zraw; sp.bc = bc; sp.dtv = dtv_arr; sp.dA = dA_arr;
  sp.D[0] = D_HF; sp.D[1] = D_HB; sp.D[2] = D_VF; sp.D[3] = D_VB;

  k_scan1<<<dim3(NCHUNK, 8, 4), 64, 0, stream>>>(sp, S, P);
  k_scan2<<<32, 512, 0, stream>>>(S, P, carry);
  k_scan3<<<dim3(NCHUNK, 8, 4), 64, 0, stream>>>(sp, carry, ybf);

  // fused out-proj + final GEMM, split by dir pair -> bf16 partials
  k_fuse<<<dim3(ROWS / 64, 2), 256, 0, stream>>>(ybf, Wt_dirs, Wt_fin, inv, pbuf);
  // sum partials -> d_out
  k_red<<<ROWS * 256 / 8 / 256, 256, 0, stream>>>(pbuf, (float*)d_out);

  (void)in_sizes; (void)n_in; (void)out_size; (void)ws_size;
}

// Round 14
// 266.893 us; speedup vs baseline: 1.0228x; 1.0228x over previous
//
#include <hip/hip_runtime.h>
#include <hip/hip_bf16.h>

// ---------------- problem constants ----------------
#define B_N 2
#define L_N 8192
#define ROWS 16384                // B_N * L_N
#define CHUNK 32
#define NCHUNK 256                // L_N / CHUNK
#define NPAD 1152                 // input-proj N padded: 2 x 544 + pad to 9*128

typedef __bf16 bf16x8 __attribute__((ext_vector_type(8)));
typedef float f32x4 __attribute__((ext_vector_type(4)));

// fast silu: 1-ulp rcp instead of IEEE divide
__device__ __forceinline__ float siluf(float v) {
  return v * __builtin_amdgcn_rcpf(1.f + __expf(-v));
}
__device__ __forceinline__ float softplusf_(float v) {
  return fmaxf(v, 0.f) + log1pf(__expf(-fabsf(v)));
}
// native bf16 convert (gfx950 HW cvt, RNE)
__device__ __forceinline__ unsigned short f2bf(float v) {
  union { __bf16 b; unsigned short u; } x;
  x.b = (__bf16)v;
  return x.u;
}
__device__ __forceinline__ float bf2f(unsigned short u) {
  union { unsigned u; float f; } x; x.u = ((unsigned)u) << 16;
  return x.f;
}

// async global->LDS, 16B per lane, LDS dest = wave-uniform base + lane*16
__device__ __forceinline__ void gload_lds16(const unsigned short* g, unsigned short* l) {
  __builtin_amdgcn_global_load_lds(
      (const __attribute__((address_space(1))) unsigned int*)g,
      (__attribute__((address_space(3))) unsigned int*)l, 16, 0, 0);
}

struct P4 { const float* p[4]; };
struct ScanConsts {
  const float* dt_bias[4];
  const float* A_log[4];
  const float* D[4];
};

// ---------------- merged prep + dtfix ----------------
// blocks [0,1024): dtfix (mat = bid>>9, rowblock = bid&511) — exact fp32 dt dot with LDS
//   staging, writes dtv/dA and xbf (bf16 cvt of x).
// blocks [1024,3328): Wt_in; [3328,4352): Wt_dirs; [4352,5376): Wt_fin; [5376,5440): inv
__global__ __launch_bounds__(256) void k_prep(
    const float* __restrict__ xH, const float* __restrict__ xV,
    const float* __restrict__ WH, const float* __restrict__ WV,
    P4 ws, const float* __restrict__ W_out, const int* __restrict__ v2h, ScanConsts sc,
    unsigned short* __restrict__ xbf, float* __restrict__ dtv_arr, float* __restrict__ dA_arr,
    unsigned short* __restrict__ Wt_in, unsigned short* __restrict__ Wt_dirs,
    unsigned short* __restrict__ Wt_fin, int* __restrict__ inv) {
  __shared__ float xs[32][257];
  __shared__ float Wsm[8][260];
  int bid = blockIdx.x;
  int tid = threadIdx.x;
  if (bid < 1024) {
    const int mat = bid >> 9;
    const float* x = mat ? xV : xH;
    const float* W = mat ? WV : WH;
    const int r0 = (bid & 511) * 32;
    for (int i = tid; i < 2048; i += 256) {
      int c = i >> 8, k = i & 255;            // c = sl*4+h
      int sl = c >> 2, h = c & 3;
      Wsm[c][k] = W[(long)k * 1064 + sl * 532 + 528 + h];
    }
    for (int i = tid; i < 32 * 64; i += 256) {
      int rl = i >> 6, kq = (i & 63) * 4;
      float4 v = *(const float4*)(x + (long)(r0 + rl) * 256 + kq);
      xs[rl][kq + 0] = v.x; xs[rl][kq + 1] = v.y; xs[rl][kq + 2] = v.z; xs[rl][kq + 3] = v.w;
    }
    __syncthreads();
    for (int i = tid; i < 32 * 64; i += 256) {
      int rl = i >> 6, kq = (i & 63) * 4;
      ushort4 o;
      o.x = f2bf(xs[rl][kq + 0]);
      o.y = f2bf(xs[rl][kq + 1]);
      o.z = f2bf(xs[rl][kq + 2]);
      o.w = f2bf(xs[rl][kq + 3]);
      *(ushort4*)(xbf + (size_t)mat * ROWS * 256 + (long)(r0 + rl) * 256 + kq) = o;
    }
    const int rl = tid >> 3, c = tid & 7;
    float s = 0.f;
    #pragma unroll 8
    for (int k = 0; k < 256; ++k) s = fmaf(xs[rl][k], Wsm[c][k], s);
    const int sl = c >> 2, h = c & 3;
    const int dir = mat * 2 + sl;
    float dtv = softplusf_(s + sc.dt_bias[dir][h]);
    float dAv = __expf(dtv * (-__expf(sc.A_log[dir][h])));
    long o = ((long)dir * 4 + h) * ROWS + (r0 + rl);
    dtv_arr[o] = dtv;
    dA_arr[o] = dAv;
  } else if (bid < 3328) {
    int i = (bid - 1024) * 256 + tid;         // 2*1152*256
    int z = i / (NPAD * 256);
    int rem = i - z * (NPAD * 256);
    int n = rem >> 8, k = rem & 255;
    const float* W = z ? WV : WH;
    int sl = n >= 544;
    int cc = n - (sl ? 544 : 0);
    float v = (cc < 532) ? W[(long)k * 1064 + sl * 532 + cc] : 0.f;
    Wt_in[i] = f2bf(v);
  } else if (bid < 4352) {
    int i = (bid - 3328) * 256 + tid;         // 4*65536
    int d = i >> 16;
    int rem = i & 65535;
    int n = rem >> 8, k = rem & 255;
    Wt_dirs[i] = f2bf(ws.p[d][(long)k * 256 + n]);
  } else if (bid < 5376) {
    int i = (bid - 4352) * 256 + tid;         // 256*1024, i = n*1024+k
    int n = i >> 10, k = i & 1023;
    Wt_fin[i] = f2bf(W_out[(long)k * 256 + n]);
  } else {
    int m = (bid - 5376) * 256 + tid;
    if (m < ROWS) {
      int b = m >> 13;
      inv[b * L_N + v2h[m]] = m;              // inverse of the v->h scatter
    }
  }
}

// ---------------- bf16 MFMA GEMM (128x128 tile, BK=32, async LDS staging) ----------------
struct EpiIn {
  unsigned short* zraw;   // [4][ROWS*256] raw z (silu applied in scans)
  unsigned short* xraw;   // [4][ROWS*256] raw x
  unsigned short* bc;     // [4][ROWS*16]  raw B|C
};

// input-proj GEMM: A row-major bf16 (lda=K=256), Bt [n][k]. Routing epilogue via
// per-wave 16-row LDS transpose; NO silu (moved to scans). Grid: x=rows, y=cols, z=mat.
__global__ __launch_bounds__(256) void k_gemm_in(
    const unsigned short* __restrict__ Abase, const unsigned short* __restrict__ Btbase,
    EpiIn ep) {
  __shared__ unsigned short As[128 * 32];
  __shared__ unsigned short Bs[128 * 32];
  __shared__ unsigned short trs[4][16 * 72];
  const int tid = threadIdx.x;
  const int lane = tid & 63;
  const int wid = tid >> 6;
  const int wm = wid & 1, wn = wid >> 1;
  const int q = lane >> 4, r = lane & 15;
  const int m0 = blockIdx.x * 128;
  const int n0 = blockIdx.y * 128;
  const int z = blockIdx.z;
  const unsigned short* A = Abase + (long)z * ROWS * 256;
  const unsigned short* Bt = Btbase + (long)z * NPAD * 256;

  f32x4 acc[4][4] = {};
  const int swr = (r >> 1) & 3;               // read-side swizzle

  for (int kt = 0; kt < 256; kt += 32) {
    #pragma unroll
    for (int i = 0; i < 2; ++i) {
      int idx = i * 256 + tid;
      int row = idx >> 2;
      int ch = (idx & 3) ^ ((row >> 1) & 3);
      gload_lds16(A + (long)(m0 + row) * 256 + kt + ch * 8,
                  &As[(size_t)(i * 256 + wid * 64) * 8]);
    }
    #pragma unroll
    for (int i = 0; i < 2; ++i) {
      int idx = i * 256 + tid;
      int row = idx >> 2;
      int ch = (idx & 3) ^ ((row >> 1) & 3);
      gload_lds16(Bt + (long)(n0 + row) * 256 + kt + ch * 8,
                  &Bs[(size_t)(i * 256 + wid * 64) * 8]);
    }
    __syncthreads();
    bf16x8 af[4], bfr[4];
    #pragma unroll
    for (int mi = 0; mi < 4; ++mi)
      af[mi] = *(const bf16x8*)&As[((wm * 64 + mi * 16 + r) * 4 + (q ^ swr)) * 8];
    #pragma unroll
    for (int ni = 0; ni < 4; ++ni)
      bfr[ni] = *(const bf16x8*)&Bs[((wn * 64 + ni * 16 + r) * 4 + (q ^ swr)) * 8];
    #pragma unroll
    for (int mi = 0; mi < 4; ++mi)
      #pragma unroll
      for (int ni = 0; ni < 4; ++ni)
        acc[mi][ni] = __builtin_amdgcn_mfma_f32_16x16x32_bf16(af[mi], bfr[ni], acc[mi][ni], 0, 0, 0);
    __syncthreads();
  }

  // per-wave dedicated transpose region: 16 rows x 72 cols (raw bf16, no silu)
  unsigned short* tr = trs[wid];
  #pragma unroll
  for (int mi = 0; mi < 4; ++mi) {
    #pragma unroll
    for (int ni = 0; ni < 4; ++ni)
      #pragma unroll
      for (int j = 0; j < 4; ++j)
        tr[(q * 4 + j) * 72 + ni * 16 + r] = f2bf(acc[mi][ni][j]);
    asm volatile("s_waitcnt lgkmcnt(0)" ::: "memory");
    #pragma unroll
    for (int pass = 0; pass < 2; ++pass) {
      int rl = pass * 8 + (lane >> 3);
      int c8 = (lane & 7) * 8;
      bf16x8 v = *(const bf16x8*)&tr[rl * 72 + c8];
      int row = m0 + wm * 64 + mi * 16 + rl;
      int col = n0 + wn * 64 + c8;
      int sl = col >= 544;
      int cc = col - (sl ? 544 : 0);
      if (cc < 528) {
        int dir = z * 2 + sl;
        if (cc < 256)
          *(bf16x8*)(ep.zraw + ((long)dir * ROWS + row) * 256 + cc) = v;
        else if (cc < 512)
          *(bf16x8*)(ep.xraw + ((long)dir * ROWS + row) * 256 + cc - 256) = v;
        else
          *(bf16x8*)(ep.bc + ((long)dir * ROWS + row) * 16 + cc - 512) = v;
      }
    }
    asm volatile("s_waitcnt lgkmcnt(0)" ::: "memory");
  }
}

// ---------------- fused out-proj + final GEMM, split by dir pair ----------------
// LDS union: As1 (y staging, dead after first GEMM) aliases Tl start -> 50.4 KB, 3 blocks/CU.
__global__ __launch_bounds__(256) void k_fuse(
    const unsigned short* __restrict__ ybf,      // [4][ROWS][256]
    const unsigned short* __restrict__ Wt_dirs,  // [4][256 n][256 k]
    const unsigned short* __restrict__ Wt_fin,   // [256 c][1024 k] (k = d*256+kk)
    const int* __restrict__ inv,
    unsigned short* __restrict__ pbuf) {         // [2][ROWS*256] bf16
  __shared__ unsigned short smem[64 * 264 + 256 * 32];
  __shared__ int arow[64];
  unsigned short* Tl = smem;                     // Tl[r][c] = Tl[r*264+c], pad 264 (16B rows)
  unsigned short* As1 = smem;                    // aliases Tl[0..2048) — disjoint lifetime
  unsigned short* Bs1 = smem + 64 * 264;         // weight staging (both gemms)
  const int tid = threadIdx.x;
  const int lane = tid & 63;
  const int wid = tid >> 6;
  const int q = lane >> 4, r = lane & 15;
  const int r0 = blockIdx.x * 64;
  const int pair = blockIdx.y;
  const int swr = (r >> 1) & 3;

  if (tid < 64) arow[tid] = pair ? inv[r0 + tid] : (r0 + tid);
  __syncthreads();

  f32x4 acc_o[4][4] = {};

  #pragma unroll
  for (int dd = 0; dd < 2; ++dd) {
    const int d = pair * 2 + dd;
    const unsigned short* yd = ybf + (long)d * ROWS * 256;
    const unsigned short* Wd = Wt_dirs + (long)d * 65536;

    f32x4 acc_t[4][4] = {};
    // ---- first GEMM: T = y_d[rows,:] @ Wd  (K=256); A in As1 (aliases Tl) ----
    for (int kt = 0; kt < 256; kt += 32) {
      {
        int row = tid >> 2;
        int ch = (tid & 3) ^ ((row >> 1) & 3);
        gload_lds16(yd + (long)arow[row] * 256 + kt + ch * 8, &As1[(size_t)(wid * 64) * 8]);
      }
      #pragma unroll
      for (int i = 0; i < 4; ++i) {
        int idx = i * 256 + tid;
        int row = idx >> 2;
        int ch = (idx & 3) ^ ((row >> 1) & 3);
        gload_lds16(Wd + (long)row * 256 + kt + ch * 8,
                    &Bs1[(size_t)(i * 256 + wid * 64) * 8]);
      }
      __syncthreads();
      bf16x8 af[4], bfr[4];
      #pragma unroll
      for (int mi = 0; mi < 4; ++mi)
        af[mi] = *(const bf16x8*)&As1[((mi * 16 + r) * 4 + (q ^ swr)) * 8];
      #pragma unroll
      for (int ni = 0; ni < 4; ++ni)
        bfr[ni] = *(const bf16x8*)&Bs1[((wid * 64 + ni * 16 + r) * 4 + (q ^ swr)) * 8];
      #pragma unroll
      for (int mi = 0; mi < 4; ++mi)
        #pragma unroll
        for (int ni = 0; ni < 4; ++ni)
          acc_t[mi][ni] = __builtin_amdgcn_mfma_f32_16x16x32_bf16(af[mi], bfr[ni], acc_t[mi][ni], 0, 0, 0);
      __syncthreads();
    }
    // ---- write silu(T) to LDS (row-major; As1 now dead) ----
    #pragma unroll
    for (int mi = 0; mi < 4; ++mi)
      #pragma unroll
      for (int ni = 0; ni < 4; ++ni)
        #pragma unroll
        for (int j = 0; j < 4; ++j)
          Tl[(mi * 16 + q * 4 + j) * 264 + wid * 64 + ni * 16 + r] = f2bf(siluf(acc_t[mi][ni][j]));
    __syncthreads();
    // ---- second GEMM: acc_o += T @ Wout[d*256+kk][c], A from Tl ----
    for (int kt = 0; kt < 256; kt += 32) {
      #pragma unroll
      for (int i = 0; i < 4; ++i) {
        int idx = i * 256 + tid;
        int row = idx >> 2;                    // out col c
        int ch = (idx & 3) ^ ((row >> 1) & 3);
        gload_lds16(Wt_fin + (long)row * 1024 + d * 256 + kt + ch * 8,
                    &Bs1[(size_t)(i * 256 + wid * 64) * 8]);
      }
      __syncthreads();
      bf16x8 af[4], bfr[4];
      #pragma unroll
      for (int mi = 0; mi < 4; ++mi)
        af[mi] = *(const bf16x8*)&Tl[(mi * 16 + r) * 264 + kt + q * 8];
      #pragma unroll
      for (int ni = 0; ni < 4; ++ni)
        bfr[ni] = *(const bf16x8*)&Bs1[((wid * 64 + ni * 16 + r) * 4 + (q ^ swr)) * 8];
      #pragma unroll
      for (int mi = 0; mi < 4; ++mi)
        #pragma unroll
        for (int ni = 0; ni < 4; ++ni)
          acc_o[mi][ni] = __builtin_amdgcn_mfma_f32_16x16x32_bf16(af[mi], bfr[ni], acc_o[mi][ni], 0, 0, 0);
      __syncthreads();
    }
  }

  // ---- output: bf16 partial via Tl transpose (wave-internal band), 16B/lane stores ----
  #pragma unroll
  for (int mi = 0; mi < 4; ++mi)
    #pragma unroll
    for (int ni = 0; ni < 4; ++ni)
      #pragma unroll
      for (int j = 0; j < 4; ++j)
        Tl[(mi * 16 + q * 4 + j) * 264 + wid * 64 + ni * 16 + r] = f2bf(acc_o[mi][ni][j]);
  asm volatile("s_waitcnt lgkmcnt(0)" ::: "memory");
  unsigned short* pout = pbuf + (long)pair * ROWS * 256;
  #pragma unroll
  for (int pass = 0; pass < 8; ++pass) {
    int rl = pass * 8 + (lane >> 3);
    int c8 = (lane & 7) * 8;
    bf16x8 v = *(const bf16x8*)&Tl[rl * 264 + wid * 64 + c8];
    *(bf16x8*)(pout + (long)(r0 + rl) * 256 + wid * 64 + c8) = v;
  }
}

// sum the two bf16 pair partials into fp32 d_out
__global__ void k_red(const unsigned short* __restrict__ pbuf, float* __restrict__ out) {
  int i = blockIdx.x * 256 + threadIdx.x;     // 8-elem group index, ROWS*256/8 total
  uint4 a = ((const uint4*)pbuf)[i];
  uint4 b = ((const uint4*)(pbuf + (size_t)ROWS * 256))[i];
  const unsigned short* au = (const unsigned short*)&a;
  const unsigned short* bu = (const unsigned short*)&b;
  float rr[8];
  #pragma unroll
  for (int j = 0; j < 8; ++j) rr[j] = bf2f(au[j]) + bf2f(bu[j]);
  ((float4*)out)[i * 2] = *(float4*)&rr[0];
  ((float4*)out)[i * 2 + 1] = *(float4*)&rr[4];
}

// ---------------- scan kernels ----------------
struct ScanP {
  const unsigned short* xraw;  // [4][ROWS*256] raw (silu applied here)
  const unsigned short* zraw;
  const unsigned short* bc;    // [4][ROWS*16] raw
  const float* dtv;            // [16][ROWS]  (dir*4+h)
  const float* dA;
  const float* D[4];
};

// phase 1: per-chunk (32 steps) local scan from zero; write end-state S and cum-dA P
__global__ __launch_bounds__(64) void k_scan1(ScanP sp, float* __restrict__ S,
                                              float* __restrict__ P) {
  __shared__ __align__(16) float Bst[CHUNK][8];
  __shared__ float dAs[CHUNK];
  const int p = threadIdx.x;
  const int c = blockIdx.x;
  const int bh = blockIdx.y;
  const int d = blockIdx.z;
  const int b = bh >> 2, h = bh & 3;
  const int rev = d & 1;
  const int t0 = c * CHUNK;
  if (p < CHUNK) {
    const int t = t0 + p;
    const int l = rev ? (L_N - 1 - t) : t;
    const int row = (b << 13) + l;
    uint4 bv = *(const uint4*)(sp.bc + ((long)d * ROWS + row) * 16);
    const unsigned short* bu = (const unsigned short*)&bv;
    float dtvv = sp.dtv[((long)d * 4 + h) * ROWS + row];
    dAs[p] = sp.dA[((long)d * 4 + h) * ROWS + row];
    #pragma unroll
    for (int n = 0; n < 8; ++n) Bst[p][n] = siluf(bf2f(bu[n])) * dtvv;
  }
  __syncthreads();

  float st[8] = {0, 0, 0, 0, 0, 0, 0, 0};
  float cumdA = 1.f;
  const int l0 = rev ? (L_N - 1 - t0) : t0;
  const unsigned short* xp = sp.xraw + ((long)d * ROWS + (b << 13) + l0) * 256 + h * 64 + p;
  const long stp = rev ? -256L : 256L;

  // double-buffered 8-step load groups
  unsigned short xa[8], xb[8];
  #pragma unroll
  for (int j = 0; j < 8; ++j) xa[j] = xp[(long)j * stp];
  #pragma unroll
  for (int g = 0; g < 4; ++g) {
    if (g < 3) {
      #pragma unroll
      for (int j = 0; j < 8; ++j) xb[j] = xp[(long)((g + 1) * 8 + j) * stp];
    }
    #pragma unroll
    for (int j = 0; j < 8; ++j) {
      int s = g * 8 + j;
      float x = siluf(bf2f(xa[j]));
      float dA = dAs[s];
      f32x4 B0 = *(const f32x4*)&Bst[s][0];
      f32x4 B1 = *(const f32x4*)&Bst[s][4];
      cumdA *= dA;
      st[0] = fmaf(dA, st[0], x * B0[0]);
      st[1] = fmaf(dA, st[1], x * B0[1]);
      st[2] = fmaf(dA, st[2], x * B0[2]);
      st[3] = fmaf(dA, st[3], x * B0[3]);
      st[4] = fmaf(dA, st[4], x * B1[0]);
      st[5] = fmaf(dA, st[5], x * B1[1]);
      st[6] = fmaf(dA, st[6], x * B1[2]);
      st[7] = fmaf(dA, st[7], x * B1[3]);
    }
    #pragma unroll
    for (int j = 0; j < 8; ++j) xa[j] = xb[j];
  }
  float* Sp = S + ((((long)d * NCHUNK + c) * 8 + bh) * 64 + p) * 8;
  #pragma unroll
  for (int n = 0; n < 8; ++n) Sp[n] = st[n];
  if (p == 0) P[((long)d * NCHUNK + c) * 8 + bh] = cumdA;
}

// phase 2: sequential chunk-level combine -> carry-in per chunk (P preloaded to LDS)
__global__ __launch_bounds__(512) void k_scan2(const float* __restrict__ S,
                                               const float* __restrict__ P,
                                               float* __restrict__ carry) {
  __shared__ float Pl[NCHUNK];
  const int tid = threadIdx.x;
  const int dbh = blockIdx.x;
  const int d = dbh >> 3, bh = dbh & 7;
  if (tid < NCHUNK) Pl[tid] = P[((long)d * NCHUNK + tid) * 8 + bh];
  __syncthreads();
  float cy = 0.f;
  carry[(((long)d * NCHUNK + 0) * 8 + bh) * 512 + tid] = 0.f;
  #pragma unroll 8
  for (int c = 1; c < NCHUNK; ++c) {
    const float Sv = S[(((long)d * NCHUNK + (c - 1)) * 8 + bh) * 512 + tid];
    cy = fmaf(Pl[c - 1], cy, Sv);
    carry[(((long)d * NCHUNK + c) * 8 + bh) * 512 + tid] = cy;
  }
}

// phase 3: re-scan with carry-in, produce gated y in bf16
__global__ __launch_bounds__(64) void k_scan3(ScanP sp, const float* __restrict__ carry,
                                              unsigned short* __restrict__ ybf) {
  __shared__ __align__(16) float Bst[CHUNK][8];
  __shared__ __align__(16) float Cst[CHUNK][8];
  __shared__ float dAs[CHUNK];
  const int p = threadIdx.x;
  const int c = blockIdx.x;
  const int bh = blockIdx.y;
  const int d = blockIdx.z;
  const int b = bh >> 2, h = bh & 3;
  const int rev = d & 1;
  const float Dv = sp.D[d][h];
  const int t0 = c * CHUNK;
  if (p < CHUNK) {
    const int t = t0 + p;
    const int l = rev ? (L_N - 1 - t) : t;
    const int row = (b << 13) + l;
    const unsigned short* bp = sp.bc + ((long)d * ROWS + row) * 16;
    uint4 bv = *(const uint4*)bp;
    uint4 cv = *(const uint4*)(bp + 8);
    const unsigned short* bu = (const unsigned short*)&bv;
    const unsigned short* cu = (const unsigned short*)&cv;
    float dtvv = sp.dtv[((long)d * 4 + h) * ROWS + row];
    dAs[p] = sp.dA[((long)d * 4 + h) * ROWS + row];
    #pragma unroll
    for (int n = 0; n < 8; ++n) Bst[p][n] = siluf(bf2f(bu[n])) * dtvv;
    #pragma unroll
    for (int n = 0; n < 8; ++n) Cst[p][n] = siluf(bf2f(cu[n]));
  }
  __syncthreads();

  float st[8];
  {
    const float* cp = carry + ((((long)d * NCHUNK + c) * 8 + bh) * 64 + p) * 8;
    #pragma unroll
    for (int n = 0; n < 8; ++n) st[n] = cp[n];
  }

  const int l0 = rev ? (L_N - 1 - t0) : t0;
  const long base = (long)(b << 13) + l0;
  const unsigned short* xp = sp.xraw + ((long)d * ROWS + base) * 256 + h * 64 + p;
  const unsigned short* zp = sp.zraw + ((long)d * ROWS + base) * 256 + h * 64 + p;
  unsigned short* yp = ybf + ((long)d * ROWS + base) * 256 + h * 64 + p;
  const long stp = rev ? -256L : 256L;

  // double-buffered 8-step load groups (x and z)
  unsigned short xa[8], xb[8], za[8], zb[8];
  #pragma unroll
  for (int j = 0; j < 8; ++j) { xa[j] = xp[(long)j * stp]; za[j] = zp[(long)j * stp]; }
  #pragma unroll
  for (int g = 0; g < 4; ++g) {
    if (g < 3) {
      #pragma unroll
      for (int j = 0; j < 8; ++j) {
        xb[j] = xp[(long)((g + 1) * 8 + j) * stp];
        zb[j] = zp[(long)((g + 1) * 8 + j) * stp];
      }
    }
    #pragma unroll
    for (int j = 0; j < 8; ++j) {
      int s = g * 8 + j;
      float x = siluf(bf2f(xa[j]));
      float zv = siluf(bf2f(za[j]));
      float dA = dAs[s];
      f32x4 B0 = *(const f32x4*)&Bst[s][0];
      f32x4 B1 = *(const f32x4*)&Bst[s][4];
      f32x4 C0 = *(const f32x4*)&Cst[s][0];
      f32x4 C1 = *(const f32x4*)&Cst[s][4];
      st[0] = fmaf(dA, st[0], x * B0[0]);
      st[1] = fmaf(dA, st[1], x * B0[1]);
      st[2] = fmaf(dA, st[2], x * B0[2]);
      st[3] = fmaf(dA, st[3], x * B0[3]);
      st[4] = fmaf(dA, st[4], x * B1[0]);
      st[5] = fmaf(dA, st[5], x * B1[1]);
      st[6] = fmaf(dA, st[6], x * B1[2]);
      st[7] = fmaf(dA, st[7], x * B1[3]);
      float y01 = fmaf(st[1], C0[1], st[0] * C0[0]);
      float y23 = fmaf(st[3], C0[3], st[2] * C0[2]);
      float y45 = fmaf(st[5], C1[1], st[4] * C1[0]);
      float y67 = fmaf(st[7], C1[3], st[6] * C1[2]);
      float y = (y01 + y23) + (y45 + y67);
      y = fmaf(Dv, x, y) * zv;
      yp[(long)s * stp] = f2bf(y);
    }
    #pragma unroll
    for (int j = 0; j < 8; ++j) { xa[j] = xb[j]; za[j] = zb[j]; }
  }
}

// ---------------- launch ----------------
extern "C" void kernel_launch(void* const* d_in, const int* in_sizes, int n_in,
                              void* d_out, int out_size, void* d_ws, size_t ws_size,
                              hipStream_t stream) {
  const float* x_H = (const float*)d_in[0];
  const float* x_V = (const float*)d_in[1];
  const float* W_in_H = (const float*)d_in[2];
  const float* W_in_V = (const float*)d_in[3];
  const float* W_out_HF = (const float*)d_in[4];
  const float* W_out_HB = (const float*)d_in[5];
  const float* W_out_VF = (const float*)d_in[6];
  const float* W_out_VB = (const float*)d_in[7];
  const float* W_out = (const float*)d_in[8];
  const float* dt_bias_HF = (const float*)d_in[9];
  const float* A_log_HF = (const float*)d_in[10];
  const float* D_HF = (const float*)d_in[11];
  const float* dt_bias_HB = (const float*)d_in[12];
  const float* A_log_HB = (const float*)d_in[13];
  const float* D_HB = (const float*)d_in[14];
  const float* dt_bias_VF = (const float*)d_in[15];
  const float* A_log_VF = (const float*)d_in[16];
  const float* D_VF = (const float*)d_in[17];
  const float* dt_bias_VB = (const float*)d_in[18];
  const float* A_log_VB = (const float*)d_in[19];
  const float* D_VB = (const float*)d_in[20];
  const int* v2h = (const int*)d_in[21];

  char* ws = (char*)d_ws;
  size_t off = 0;
  auto alloc = [&](size_t bytes) {
    void* pp = ws + off;
    off = (off + bytes + 255) & ~(size_t)255;
    return pp;
  };
  unsigned short* xbf = (unsigned short*)alloc((size_t)2 * ROWS * 256 * 2);      // [2 mats]
  unsigned short* Wt_in = (unsigned short*)alloc((size_t)2 * NPAD * 256 * 2);    // [2 mats]
  unsigned short* Wt_dirs = (unsigned short*)alloc((size_t)4 * 65536 * 2);
  unsigned short* Wt_fin = (unsigned short*)alloc((size_t)256 * 1024 * 2);
  unsigned short* zraw = (unsigned short*)alloc((size_t)4 * ROWS * 256 * 2);
  unsigned short* xraw = (unsigned short*)alloc((size_t)4 * ROWS * 256 * 2);
  unsigned short* bc = (unsigned short*)alloc((size_t)4 * ROWS * 16 * 2);
  float* dtv_arr = (float*)alloc((size_t)16 * ROWS * 4);
  float* dA_arr = (float*)alloc((size_t)16 * ROWS * 4);
  unsigned short* ybf = (unsigned short*)alloc((size_t)4 * ROWS * 256 * 2);
  float* S = (float*)alloc((size_t)4 * NCHUNK * 8 * 512 * 4);
  float* P = (float*)alloc((size_t)4 * NCHUNK * 8 * 4);
  float* carry = (float*)alloc((size_t)4 * NCHUNK * 8 * 512 * 4);
  int* inv = (int*)alloc((size_t)ROWS * 4);
  unsigned short* pbuf = (unsigned short*)alloc((size_t)2 * ROWS * 256 * 2);

  ScanConsts sc;
  sc.dt_bias[0] = dt_bias_HF; sc.dt_bias[1] = dt_bias_HB;
  sc.dt_bias[2] = dt_bias_VF; sc.dt_bias[3] = dt_bias_VB;
  sc.A_log[0] = A_log_HF; sc.A_log[1] = A_log_HB;
  sc.A_log[2] = A_log_VF; sc.A_log[3] = A_log_VB;
  sc.D[0] = D_HF; sc.D[1] = D_HB; sc.D[2] = D_VF; sc.D[3] = D_VB;

  P4 wdirs;  // cat order: dir0 HF->W_out_HB, dir1 HB->W_out_HF, dir2 VF->W_out_VB, dir3 VB->W_out_VF
  wdirs.p[0] = W_out_HB; wdirs.p[1] = W_out_HF; wdirs.p[2] = W_out_VB; wdirs.p[3] = W_out_VF;

  // merged prep: dtfix (+x cvt) | weights | inv
  k_prep<<<5440, 256, 0, stream>>>(x_H, x_V, W_in_H, W_in_V, wdirs, W_out, v2h, sc,
                                   xbf, dtv_arr, dA_arr, Wt_in, Wt_dirs, Wt_fin, inv);

  EpiIn ep; ep.zraw = zraw; ep.xraw = xraw; ep.bc = bc;

  // input GEMMs (batched over 2 mats), routing epilogue -> raw bf16 z/x/bc
  k_gemm_in<<<dim3(ROWS / 128, NPAD / 128, 2), 256, 0, stream>>>(xbf, Wt_in, ep);

  ScanP sp;
  sp.xraw = xraw; sp.zraw = zraw; sp.bc = bc; sp.dtv = dtv_arr; sp.dA = dA_arr;
  sp.D[0] = D_HF; sp.D[1] = D_HB; sp.D[2] = D_VF; sp.D[3] = D_VB;

  k_scan1<<<dim3(NCHUNK, 8, 4), 64, 0, stream>>>(sp, S, P);
  k_scan2<<<32, 512, 0, stream>>>(S, P, carry);
  k_scan3<<<dim3(NCHUNK, 8, 4), 64, 0, stream>>>(sp, carry, ybf);

  // fused out-proj + final GEMM, split by dir pair -> bf16 partials
  k_fuse<<<dim3(ROWS / 64, 2), 256, 0, stream>>>(ybf, Wt_dirs, Wt_fin, inv, pbuf);
  // sum partials -> d_out
  k_red<<<ROWS * 256 / 8 / 256, 256, 0, stream>>>(pbuf, (float*)d_out);

  (void)in_sizes; (void)n_in; (void)out_size; (void)ws_size;
}